// Round 6
// baseline (225.094 us; speedup 1.0000x reference)
//
#include <hip/hip_runtime.h>
#include <math.h>

// MoE router: logits = x[16384,2048] @ W^T[2048,64]; softmax; top-2; renorm.
//
// R5 post-mortem: structure right (VGPR 52, no spill, 80.5us) but grid only
// supplied 2 waves/SIMD (Occupancy 20.6%) -> latency-bound on B-from-L2
// stalls (VALUBusy 11%). R6: 8-wave blocks (eh 2 expert-halves x kq 4
// K-quarters) -> 16 waves/CU = 4 waves/SIMD, plus explicit depth-1 register
// double-buffering of BOTH A and B so L2/HBM latency is off the critical path.
//
// fp16 split-precision MFMA: x = xh+xl, W = wh+wl; logits = xh*wh+xl*wh+xh*wl
// (3 passes, fp32 acc) -> ~2.4e-7 logit RMS, below fp32 reassoc noise.
// MFMA 16x16x32 f16 operand layout: A[m=lane&15][k=(lane>>4)*8+j] (B same on n);
// C/D: n=lane&15, m=(lane>>4)*4+reg.
// Wave = 32 tok x 32 exp x 512 k, no LDS/barriers in the K-loop; kq partials
// combine through a small LDS slab. W pre-split to fp16 hi/lo by w_split
// (512KB, L2-resident).

typedef _Float16 half8  __attribute__((ext_vector_type(8)));
typedef float    floatx4 __attribute__((ext_vector_type(4)));

#define NTOK 16384
#define DDIM 2048
#define NE   64
#define NSTEP 16   // 512 k per wave / 32 k per mfma step

// ---- kernel 1: split W fp32 -> fp16 hi + lo (64x2048 = 131072 elems) ----
__global__ __launch_bounds__(256) void w_split(const float* __restrict__ W,
                                               _Float16* __restrict__ whi,
                                               _Float16* __restrict__ wlo) {
    const int g = (blockIdx.x * 256 + threadIdx.x) * 8;
    const float4 v0 = *(const float4*)(W + g);
    const float4 v1 = *(const float4*)(W + g + 4);
    float f[8] = {v0.x, v0.y, v0.z, v0.w, v1.x, v1.y, v1.z, v1.w};
    half8 hi, lo;
#pragma unroll
    for (int j = 0; j < 8; ++j) {
        const _Float16 h = (_Float16)f[j];
        hi[j] = h;
        lo[j] = (_Float16)(f[j] - (float)h);
    }
    *(half8*)(whi + g) = hi;
    *(half8*)(wlo + g) = lo;
}

// ---- kernel 2: GEMM + softmax + top-2 ----
__global__ __launch_bounds__(512) void router_mfma(
    const float* __restrict__ x,
    const _Float16* __restrict__ whi,
    const _Float16* __restrict__ wlo,
    float* __restrict__ out)
{
    __shared__ float ex[3 * 2 * 64 * 20];  // kq-exchange [kq-1][eh][lane][16+4]
    __shared__ float lg[32 * 68];          // logits slab [m][64+4pad]

    const int tid = threadIdx.x;
    const int L   = tid & 63;
    const int wv  = __builtin_amdgcn_readfirstlane(tid >> 6);
    const int eh  = wv & 1;            // expert half: n in [32*eh, 32*eh+32)
    const int kq  = wv >> 1;           // K quarter: k in [512*kq, 512*kq+512)
    const int c   = L & 15;            // frag row (m or n)
    const int q   = L >> 4;            // frag quad -> k = q*8 + j
    const int tok0 = blockIdx.x * 32;
    const int kb   = kq * 512;

    // global frag base pointers (per-lane)
    const float*    ax0 = x   + (size_t)(tok0 + c) * DDIM + kb + q * 8;
    const float*    ax1 = ax0 + 16 * DDIM;
    const _Float16* b0h = whi + (size_t)(eh * 32 + c) * DDIM + kb + q * 8;
    const _Float16* b1h = b0h + 16 * DDIM;
    const _Float16* b0l = wlo + (size_t)(eh * 32 + c) * DDIM + kb + q * 8;
    const _Float16* b1l = b0l + 16 * DDIM;

    // depth-1 register double buffers for A and B
    float4 pa[2][2][2];       // [buf][mt][half of 8 floats]
    half8  pbh[2][2], pbl[2][2];  // [buf][nt]

    pa[0][0][0] = *(const float4*)(ax0);
    pa[0][0][1] = *(const float4*)(ax0 + 4);
    pa[0][1][0] = *(const float4*)(ax1);
    pa[0][1][1] = *(const float4*)(ax1 + 4);
    pbh[0][0] = *(const half8*)(b0h);
    pbh[0][1] = *(const half8*)(b1h);
    pbl[0][0] = *(const half8*)(b0l);
    pbl[0][1] = *(const half8*)(b1l);

    floatx4 acc[2][2];    // [mt][nt]
#pragma unroll
    for (int i = 0; i < 2; ++i)
#pragma unroll
        for (int j = 0; j < 2; ++j) acc[i][j] = (floatx4)0.f;

#pragma unroll 2
    for (int s = 0; s < NSTEP; ++s) {
        const int cur = s & 1, nxt = cur ^ 1;

        // prefetch step s+1 (A from HBM/L3, B from L2); consumed next iter,
        // so the compiler's waitcnt before use lets these stay in flight
        if (s + 1 < NSTEP) {
            const int on = (s + 1) * 32;
            pa[nxt][0][0] = *(const float4*)(ax0 + on);
            pa[nxt][0][1] = *(const float4*)(ax0 + on + 4);
            pa[nxt][1][0] = *(const float4*)(ax1 + on);
            pa[nxt][1][1] = *(const float4*)(ax1 + on + 4);
            pbh[nxt][0] = *(const half8*)(b0h + on);
            pbh[nxt][1] = *(const half8*)(b1h + on);
            pbl[nxt][0] = *(const half8*)(b0l + on);
            pbl[nxt][1] = *(const half8*)(b1l + on);
        }

        // convert A(s): fp32 -> hi/lo fp16 frags
        half8 ah[2], al[2];
#pragma unroll
        for (int mt = 0; mt < 2; ++mt) {
            const float4 u = pa[cur][mt][0];
            const float4 v = pa[cur][mt][1];
            float f[8] = {u.x, u.y, u.z, u.w, v.x, v.y, v.z, v.w};
#pragma unroll
            for (int j = 0; j < 8; ++j) {
                const _Float16 h = (_Float16)f[j];
                ah[mt][j] = h;
                al[mt][j] = (_Float16)(f[j] - (float)h);
            }
        }

        // 3-pass split MFMA: hh + lh + hl
#pragma unroll
        for (int mt = 0; mt < 2; ++mt) {
            acc[mt][0] = __builtin_amdgcn_mfma_f32_16x16x32_f16(ah[mt], pbh[cur][0], acc[mt][0], 0, 0, 0);
            acc[mt][0] = __builtin_amdgcn_mfma_f32_16x16x32_f16(al[mt], pbh[cur][0], acc[mt][0], 0, 0, 0);
            acc[mt][0] = __builtin_amdgcn_mfma_f32_16x16x32_f16(ah[mt], pbl[cur][0], acc[mt][0], 0, 0, 0);
            acc[mt][1] = __builtin_amdgcn_mfma_f32_16x16x32_f16(ah[mt], pbh[cur][1], acc[mt][1], 0, 0, 0);
            acc[mt][1] = __builtin_amdgcn_mfma_f32_16x16x32_f16(al[mt], pbh[cur][1], acc[mt][1], 0, 0, 0);
            acc[mt][1] = __builtin_amdgcn_mfma_f32_16x16x32_f16(ah[mt], pbl[cur][1], acc[mt][1], 0, 0, 0);
        }
    }

    // ---- combine K quarters through LDS: kq 1..3 store, kq 0 reduces ----
    if (kq != 0) {
        float* p = &ex[(((kq - 1) * 2 + eh) * 64 + L) * 20];
        *(float4*)(p + 0)  = make_float4(acc[0][0][0], acc[0][0][1], acc[0][0][2], acc[0][0][3]);
        *(float4*)(p + 4)  = make_float4(acc[0][1][0], acc[0][1][1], acc[0][1][2], acc[0][1][3]);
        *(float4*)(p + 8)  = make_float4(acc[1][0][0], acc[1][0][1], acc[1][0][2], acc[1][0][3]);
        *(float4*)(p + 12) = make_float4(acc[1][1][0], acc[1][1][1], acc[1][1][2], acc[1][1][3]);
    }
    __syncthreads();
    if (kq == 0) {
#pragma unroll
        for (int kk = 0; kk < 3; ++kk) {
            const float* p = &ex[((kk * 2 + eh) * 64 + L) * 20];
            float4 t;
            t = *(const float4*)(p + 0);  acc[0][0][0] += t.x; acc[0][0][1] += t.y; acc[0][0][2] += t.z; acc[0][0][3] += t.w;
            t = *(const float4*)(p + 4);  acc[0][1][0] += t.x; acc[0][1][1] += t.y; acc[0][1][2] += t.z; acc[0][1][3] += t.w;
            t = *(const float4*)(p + 8);  acc[1][0][0] += t.x; acc[1][0][1] += t.y; acc[1][0][2] += t.z; acc[1][0][3] += t.w;
            t = *(const float4*)(p + 12); acc[1][1][0] += t.x; acc[1][1][1] += t.y; acc[1][1][2] += t.z; acc[1][1][3] += t.w;
        }
        // scatter to logits slab: C/D layout n=lane&15, m=(lane>>4)*4+reg
#pragma unroll
        for (int mt = 0; mt < 2; ++mt)
#pragma unroll
            for (int nt = 0; nt < 2; ++nt)
#pragma unroll
                for (int r = 0; r < 4; ++r)
                    lg[(mt * 16 + q * 4 + r) * 68 + eh * 32 + nt * 16 + c] = acc[mt][nt][r];
    }
    __syncthreads();

    // ---- softmax + top-2: thread t < 32 owns token tok0+t ----
    if (tid < 32) {
        const int token = tok0 + tid;
        float* row = &lg[tid * 68];
        float p[NE];
#pragma unroll
        for (int e = 0; e < NE; ++e) p[e] = row[e];

        float m = p[0];
#pragma unroll
        for (int e = 1; e < NE; ++e) m = fmaxf(m, p[e]);
        float s = 0.f;
#pragma unroll
        for (int e = 0; e < NE; ++e) { p[e] = expf(p[e] - m); s += p[e]; }
        const float inv = 1.f / s;

        // lax.top_k tie-break = lowest index first -> strict '>' ascending scan
        float v1 = -1.f; int i1 = 0;
#pragma unroll
        for (int e = 0; e < NE; ++e) { if (p[e] > v1) { v1 = p[e]; i1 = e; } }
        float v2 = -1.f; int i2 = 0;
#pragma unroll
        for (int e = 0; e < NE; ++e) { if (e != i1 && p[e] > v2) { v2 = p[e]; i2 = e; } }

        const float ts = v1 + v2;
        float* out_tp = out;              // top_k_probs  [NTOK][2]
        float* out_ti = out + 2 * NTOK;   // top_k_indices[NTOK][2] (float values)
        *(float2*)(out_tp + token * 2) = make_float2(v1 / ts, v2 / ts);
        *(float2*)(out_ti + token * 2) = make_float2((float)i1, (float)i2);

        // renormalized probs back into the slab for a coalesced block write
#pragma unroll
        for (int e = 0; e < NE; ++e) row[e] = p[e] * inv;
    }
    __syncthreads();

    // ---- cooperative coalesced probs write: 32 tok x 64 = 2048 floats ----
    {
        float* out_p = out + 4 * NTOK + (size_t)tok0 * NE;
        const int f  = tid;                 // float4 index, 512 total
        const int r  = f >> 4, c4 = f & 15;
        const float4 v = *(const float4*)&lg[r * 68 + 4 * c4];
        *(float4*)(out_p + f * 4) = v;
    }
}

extern "C" void kernel_launch(void* const* d_in, const int* in_sizes, int n_in,
                              void* d_out, int out_size, void* d_ws, size_t ws_size,
                              hipStream_t stream) {
    const float* x = (const float*)d_in[0];
    const float* W = (const float*)d_in[1];
    float* out     = (float*)d_out;
    _Float16* whi  = (_Float16*)d_ws;          // 256 KB
    _Float16* wlo  = whi + (size_t)NE * DDIM;  // 256 KB (ws >= 512 KB)

    w_split<<<dim3(64), dim3(256), 0, stream>>>(W, whi, wlo);
    router_mfma<<<dim3(NTOK / 32), dim3(512), 0, stream>>>(x, whi, wlo, out);
}

// Round 7
// 211.981 us; speedup vs baseline: 1.0619x; 1.0619x over previous
//
#include <hip/hip_runtime.h>
#include <math.h>

// MoE router: logits = x[16384,2048] @ W^T[2048,64]; softmax; top-2; renorm.
//
// R6 post-mortem: per-CU totals (2048 small vmem instrs) and dur identical
// across 2x occupancy -> per-CU memory-request throughput wall (~100 cyc/instr),
// W re-fetched 256MB from L2 as per-wave frag loads. R7 = m97-style staging:
// both operands stream through double-buffered LDS; frag reads are
// ds_read_b128 with an XOR granule swizzle (8 dwords/bank = conflict-free).
//
// fp16 split-precision MFMA (verified R5/R6, absmax 0.002): x=xh+xl, W=wh+wl,
// logits = xh*wh + xl*wh + xh*wl, fp32 acc.
// Block: 64 tok x 64 exp x K2048, 512thr = 8 waves = (mh,nh,kh) each M32xN32xK32
// per 64-k step; grid 256 = 1 block/CU. W pre-split+pre-swizzled into a 512KB
// image by w_split so router staging is a pure coalesced 16B/lane copy.
//
// LDS swizzle: tile = 64 rows x 8 granules (granule = 8 fp16 = 16B).
// Slot (r,g) holds source granule g^(r&7). Frag read (row r, want granule gs)
// reads slot gs^(r&7): bank-group = gs^(L&7) -> 8 lanes/group = b128 baseline.

typedef _Float16 half8  __attribute__((ext_vector_type(8)));
typedef float    floatx4 __attribute__((ext_vector_type(4)));

#define NTOK  16384
#define DDIM  2048
#define NE    64
#define TPB   64     // tokens per block
#define NSTEP 32     // K tiles of 64

__device__ inline void split8(const float4& a, const float4& b,
                              half8& hi, half8& lo) {
    float f[8] = {a.x, a.y, a.z, a.w, b.x, b.y, b.z, b.w};
#pragma unroll
    for (int j = 0; j < 8; ++j) {
        const _Float16 h = (_Float16)f[j];
        hi[j] = h;
        lo[j] = (_Float16)(f[j] - (float)h);
    }
}

// ---- kernel 1: pre-split + pre-swizzle W into the staging image ----
// img granule idx = step*1024 + half*512 + e*8 + g ; contents =
// (hi|lo fp16 of) W[e][step*64 + 8*(g^(e&7)) .. +8]
__global__ __launch_bounds__(256) void w_split(const float* __restrict__ W,
                                               _Float16* __restrict__ img) {
    const int idx  = blockIdx.x * 256 + threadIdx.x;  // 0..32767
    const int step = idx >> 10;
    const int u    = idx & 1023;
    const int hl   = u >> 9;
    const int v    = u & 511;
    const int e    = v >> 3, g = v & 7;
    const float* src = W + (size_t)e * DDIM + step * 64 + 8 * (g ^ (e & 7));
    const float4 a = *(const float4*)(src);
    const float4 b = *(const float4*)(src + 4);
    half8 hi, lo;
    split8(a, b, hi, lo);
    *(half8*)(img + (size_t)idx * 8) = (hl == 0) ? hi : lo;
}

// ---- kernel 2: staged MFMA GEMM + softmax + top-2 ----
__global__ __launch_bounds__(512) void router_mfma(
    const float* __restrict__ x,
    const _Float16* __restrict__ img,
    float* __restrict__ out)
{
    __shared__ __align__(16) float tiles[16384];  // 2 x 32KB: [xhi|xlo|whi|wlo]
    __shared__ __align__(16) float lg[TPB * 68];  // logits slab, 68-pad

    const int tid = threadIdx.x;
    const int L   = tid & 63;
    const int wv  = __builtin_amdgcn_readfirstlane(tid >> 6);
    const int kh  = wv & 1;          // k half of the 64-k step
    const int nh  = (wv >> 1) & 1;   // expert 32-half
    const int mh  = wv >> 2;         // token 32-half
    const int c   = L & 15, q = L >> 4;
    const int tok0 = blockIdx.x * TPB;

    // frag LDS offsets (fp16 elems within an 8KB tile); row&7 == L&7
    const int gfrag = (q + 4 * kh) ^ (L & 7);
    int aoff[2], boff[2];
#pragma unroll
    for (int mt = 0; mt < 2; ++mt)
        aoff[mt] = ((mh * 32 + mt * 16 + c) * 8 + gfrag) * 8;
#pragma unroll
    for (int nt = 0; nt < 2; ++nt)
        boff[nt] = ((nh * 32 + nt * 16 + c) * 8 + gfrag) * 8;

    // staging map: thread -> (row sr, slot-granule so); source granule so^(sr&7)
    const int sr = tid >> 3, so = tid & 7;
    const float* xsrc = x + (size_t)(tok0 + sr) * DDIM + 8 * (so ^ (sr & 7));
    const int    xdst = (sr * 8 + so) * 8;      // fp16 elem offset in x tile
    const float* wsrc = (const float*)img;      // move granules as raw float4

    // ---- prologue: stage tile 0 into buffer 0 ----
    {
        const float4 xa  = *(const float4*)(xsrc);
        const float4 xb  = *(const float4*)(xsrc + 4);
        const float4 wh4 = *(const float4*)(wsrc + (size_t)tid * 4);
        const float4 wl4 = *(const float4*)(wsrc + (size_t)(512 + tid) * 4);
        _Float16* nb = (_Float16*)&tiles[0];
        half8 hi, lo; split8(xa, xb, hi, lo);
        *(half8*)(nb + xdst)        = hi;
        *(half8*)(nb + 4096 + xdst) = lo;
        *(float4*)(nb + 8192  + tid * 8) = wh4;   // raw fp16 granule
        *(float4*)(nb + 12288 + tid * 8) = wl4;
    }
    __syncthreads();

    floatx4 acc[2][2];
#pragma unroll
    for (int i = 0; i < 2; ++i)
#pragma unroll
        for (int j = 0; j < 2; ++j) acc[i][j] = (floatx4)0.f;

#pragma unroll 2
    for (int t = 0; t < NSTEP; ++t) {
        // issue next-tile loads first (latency hides under MFMAs)
        float4 xa, xb, wh4, wl4;
        if (t + 1 < NSTEP) {
            xa  = *(const float4*)(xsrc + (t + 1) * 64);
            xb  = *(const float4*)(xsrc + (t + 1) * 64 + 4);
            wh4 = *(const float4*)(wsrc + (size_t)((t + 1) * 1024 + tid) * 4);
            wl4 = *(const float4*)(wsrc + (size_t)((t + 1) * 1024 + 512 + tid) * 4);
        }

        // compute on buffer t&1
        const _Float16* base = (const _Float16*)&tiles[(t & 1) * 8192];
        const _Float16* xh = base;
        const _Float16* xl = base + 4096;
        const _Float16* wh = base + 8192;
        const _Float16* wl = base + 12288;

        half8 Ah[2], Al[2], Bh[2], Bl[2];
#pragma unroll
        for (int mt = 0; mt < 2; ++mt) {
            Ah[mt] = *(const half8*)(xh + aoff[mt]);
            Al[mt] = *(const half8*)(xl + aoff[mt]);
        }
#pragma unroll
        for (int nt = 0; nt < 2; ++nt) {
            Bh[nt] = *(const half8*)(wh + boff[nt]);
            Bl[nt] = *(const half8*)(wl + boff[nt]);
        }
#pragma unroll
        for (int mt = 0; mt < 2; ++mt)
#pragma unroll
            for (int nt = 0; nt < 2; ++nt) {
                acc[mt][nt] = __builtin_amdgcn_mfma_f32_16x16x32_f16(Ah[mt], Bh[nt], acc[mt][nt], 0, 0, 0);
                acc[mt][nt] = __builtin_amdgcn_mfma_f32_16x16x32_f16(Al[mt], Bh[nt], acc[mt][nt], 0, 0, 0);
                acc[mt][nt] = __builtin_amdgcn_mfma_f32_16x16x32_f16(Ah[mt], Bl[nt], acc[mt][nt], 0, 0, 0);
            }

        // stage next tile into the other buffer (free: it was read in step t-1)
        if (t + 1 < NSTEP) {
            _Float16* nb = (_Float16*)&tiles[((t + 1) & 1) * 8192];
            half8 hi, lo; split8(xa, xb, hi, lo);
            *(half8*)(nb + xdst)        = hi;
            *(half8*)(nb + 4096 + xdst) = lo;
            *(float4*)(nb + 8192  + tid * 8) = wh4;
            *(float4*)(nb + 12288 + tid * 8) = wl4;
        }
        __syncthreads();
    }

    // ---- kh-pair reduction (exchange slab aliases the tile buffers) ----
    float* exch = tiles;
    const int p = wv >> 1;   // pair id = mh*2+nh for both kh
    if (kh == 1) {
        float* e0 = &exch[(p * 64 + L) * 20];
        *(float4*)(e0 + 0)  = make_float4(acc[0][0][0], acc[0][0][1], acc[0][0][2], acc[0][0][3]);
        *(float4*)(e0 + 4)  = make_float4(acc[0][1][0], acc[0][1][1], acc[0][1][2], acc[0][1][3]);
        *(float4*)(e0 + 8)  = make_float4(acc[1][0][0], acc[1][0][1], acc[1][0][2], acc[1][0][3]);
        *(float4*)(e0 + 12) = make_float4(acc[1][1][0], acc[1][1][1], acc[1][1][2], acc[1][1][3]);
    }
    __syncthreads();
    if (kh == 0) {
        const float* e0 = &exch[(p * 64 + L) * 20];
        float4 v;
        v = *(const float4*)(e0 + 0);  acc[0][0][0] += v.x; acc[0][0][1] += v.y; acc[0][0][2] += v.z; acc[0][0][3] += v.w;
        v = *(const float4*)(e0 + 4);  acc[0][1][0] += v.x; acc[0][1][1] += v.y; acc[0][1][2] += v.z; acc[0][1][3] += v.w;
        v = *(const float4*)(e0 + 8);  acc[1][0][0] += v.x; acc[1][0][1] += v.y; acc[1][0][2] += v.z; acc[1][0][3] += v.w;
        v = *(const float4*)(e0 + 12); acc[1][1][0] += v.x; acc[1][1][1] += v.y; acc[1][1][2] += v.z; acc[1][1][3] += v.w;
        // scatter: C/D layout col(n)=lane&15, row(m)=(lane>>4)*4+reg
#pragma unroll
        for (int mt = 0; mt < 2; ++mt)
#pragma unroll
            for (int nt = 0; nt < 2; ++nt)
#pragma unroll
                for (int r = 0; r < 4; ++r)
                    lg[(mh * 32 + mt * 16 + q * 4 + r) * 68 + nh * 32 + nt * 16 + c] = acc[mt][nt][r];
    }
    __syncthreads();

    // ---- softmax + top-2: thread t < 64 owns token tok0+t ----
    if (tid < 64) {
        const int token = tok0 + tid;
        float* row = &lg[tid * 68];
        float pr[NE];
#pragma unroll
        for (int e = 0; e < NE; ++e) pr[e] = row[e];

        float m = pr[0];
#pragma unroll
        for (int e = 1; e < NE; ++e) m = fmaxf(m, pr[e]);
        float s = 0.f;
#pragma unroll
        for (int e = 0; e < NE; ++e) { pr[e] = expf(pr[e] - m); s += pr[e]; }
        const float inv = 1.f / s;

        // lax.top_k tie-break = lowest index first -> strict '>' ascending scan
        float v1 = -1.f; int i1 = 0;
#pragma unroll
        for (int e = 0; e < NE; ++e) { if (pr[e] > v1) { v1 = pr[e]; i1 = e; } }
        float v2 = -1.f; int i2 = 0;
#pragma unroll
        for (int e = 0; e < NE; ++e) { if (e != i1 && pr[e] > v2) { v2 = pr[e]; i2 = e; } }

        const float ts = v1 + v2;
        float* out_tp = out;              // top_k_probs  [NTOK][2]
        float* out_ti = out + 2 * NTOK;   // top_k_indices[NTOK][2] (float values)
        *(float2*)(out_tp + token * 2) = make_float2(v1 / ts, v2 / ts);
        *(float2*)(out_ti + token * 2) = make_float2((float)i1, (float)i2);

#pragma unroll
        for (int e = 0; e < NE; ++e) row[e] = pr[e] * inv;
    }
    __syncthreads();

    // ---- cooperative coalesced probs write: 64 tok x 64 = 4096 floats ----
    {
        float* out_p = out + 4 * NTOK + (size_t)tok0 * NE;
#pragma unroll
        for (int i = 0; i < 2; ++i) {
            const int f = tid + 512 * i;        // float4 idx, 1024 total
            const int r = f >> 4, c4 = f & 15;
            const float4 v = *(const float4*)&lg[r * 68 + 4 * c4];
            *(float4*)(out_p + f * 4) = v;
        }
    }
}

extern "C" void kernel_launch(void* const* d_in, const int* in_sizes, int n_in,
                              void* d_out, int out_size, void* d_ws, size_t ws_size,
                              hipStream_t stream) {
    const float* x = (const float*)d_in[0];
    const float* W = (const float*)d_in[1];
    float* out     = (float*)d_out;
    _Float16* img  = (_Float16*)d_ws;   // 512 KB pre-swizzled W image

    w_split<<<dim3(128), dim3(256), 0, stream>>>(W, img);
    router_mfma<<<dim3(NTOK / TPB), dim3(512), 0, stream>>>(x, img, out);
}